// Round 5
// baseline (285.730 us; speedup 1.0000x reference)
//
#include <hip/hip_runtime.h>
#include <stdint.h>

#define H 192
#define W 192
#define CIN 32
#define NOUT 32
#define NB 16
#define PADI 4
#define HP 200          // padded rows
#define WP 200          // padded cols

#define HT 16           // output rows per block
#define WT2 32          // output cols per block (32-wide tile: N=32 pixels = 1 row)
#define RROWS 24        // HT + 8 halo
#define RC2 40          // WT2 + 8 halo
#define NT2 (NB * (H / HT) * (W / WT2))   // 16*12*6 = 1152

// legacy-path tile
#define WTL 16
#define RCOLS 24

typedef __attribute__((ext_vector_type(8))) short bf16x8;
typedef __attribute__((ext_vector_type(4))) float f32x4;
typedef __attribute__((ext_vector_type(16))) float f32x16;

__device__ __forceinline__ unsigned short f2bf(float f) {
    union { float f; unsigned int u; } v; v.f = f;
    unsigned int r = v.u + 0x7fffu + ((v.u >> 16) & 1u);
    return (unsigned short)(r >> 16);
}

__device__ __forceinline__ void gload_lds16(const void* g, void* l) {
    __builtin_amdgcn_global_load_lds(
        (const __attribute__((address_space(1))) void*)g,
        (__attribute__((address_space(3))) void*)l, 16, 0, 0);
}

// ---- Gaussian kernel generation, 32x32x16 layout ----
// W3[tap][half][oct][och][j] (bf16): half=ch/16, oct=(ch>>3)&1, j=ch&7.
// Per-lane A-frag (och=lane&31, k=8*oct+j, ch=half*16+k): frag idx =
// (tap*2+half)*64 + oct*32 + och.
__global__ void genw32_kernel(const float* __restrict__ wp, unsigned short* __restrict__ W3) {
    const int b = blockIdx.x;          // = o*32 + i
    const int o = b >> 5;
    const int i = b & 31;
    const int t = threadIdx.x;         // 0..127

    float sx = wp[b * 3 + 0], sy = wp[b * 3 + 1], th = wp[b * 3 + 2];
    float rad = th / 180.0f * 3.14159265358979323846f;
    float co = cosf(rad), si = sinf(rad);
    float sx2 = sx * sx, sy2 = sy * sy;
    float a = co * co * sx2 + si * si * sy2;
    float bb = co * si * (sx2 - sy2);
    float d = si * si * sx2 + co * co * sy2;
    float det = a * d - bb * bb;
    float ia = d / det, ib = -bb / det, idd = a / det;

    const int tap = t;
    float e = 0.0f;
    if (tap < 81) {
        float xx = (float)(tap % 9 - 4);
        float yy = (float)(tap / 9 - 4);
        float q = ia * xx * xx + 2.0f * ib * xx * yy + idd * yy * yy;
        e = expf(-0.5f * q);
    }
    float s = e;
    #pragma unroll
    for (int off = 32; off > 0; off >>= 1) s += __shfl_down(s, off);
    __shared__ float ws[2];
    if ((t & 63) == 0) ws[t >> 6] = s;
    __syncthreads();
    float total = ws[0] + ws[1];

    if (tap < 81) {
        const int half = i >> 4, oct = (i >> 3) & 1, j = i & 7;
        W3[((((tap * 2 + half) * 2 + oct) * 32 + o) << 3) + j] = f2bf(e / total);
    }
}

// ---- Pre-pass: NCHW fp32 -> zero-padded channel-blocked bf16 (R1-proven) ----
// xb layout: [n][quad][rp 200][wp 200][8ch]
__global__ __launch_bounds__(256) void xpad_kernel(
    const float* __restrict__ x, unsigned short* __restrict__ xb)
{
    const int gid = blockIdx.x * 256 + threadIdx.x;   // 0 .. 16*4*200*200-1
    const int wpix = gid % WP;
    int rest = gid / WP;
    const int rp = rest % HP;
    rest /= HP;
    const int quad = rest & 3;
    const int n = rest >> 2;

    const int row = rp - PADI;
    const int col = wpix - PADI;

    unsigned int d[4] = {0u, 0u, 0u, 0u};
    if ((unsigned)row < (unsigned)H && (unsigned)col < (unsigned)W) {
        const float* p = x + (((size_t)(n * CIN + quad * 8)) * H + row) * (size_t)W + col;
        float v[8];
        #pragma unroll
        for (int k = 0; k < 8; k++) v[k] = p[(size_t)k * H * W];
        #pragma unroll
        for (int k = 0; k < 4; k++)
            d[k] = (unsigned int)f2bf(v[2 * k]) | ((unsigned int)f2bf(v[2 * k + 1]) << 16);
    }
    *(uint4*)&xb[(size_t)gid * 8] = make_uint4(d[0], d[1], d[2], d[3]);
}

// ---- Conv kernel: 32x32x16 MFMA, 16x32 tile, 512 thr = 8 waves x 2 rows ----
// M=32 och (no mt split), N=32 pixels = one tile row (dy-sliding stays
// aligned), K=16 = channel half; halves accumulate into the same acc.
// Per (dx,half) unit: 10 ds_read_b128 (imm offsets) -> 18 MFMAs; A dbuf
// alternates across the 18 units. Bias folded into acc init.
__global__ __launch_bounds__(512, 4) void conv_kernel(
    const unsigned short* __restrict__ xb, const unsigned short* __restrict__ W3,
    const float* __restrict__ bias, float* __restrict__ out)
{
    __shared__ __align__(16) unsigned short ldsx[4 * RROWS * RC2 * 8];  // 61,440 B

    const int t = threadIdx.x;
    // XCD-contiguous swizzle: 8 classes x 144 tiles
    const int bid = (blockIdx.x & 7) * (NT2 / 8) + (blockIdx.x >> 3);
    const int wb = bid % (W / WT2);                 // 0..5
    const int hb = (bid / (W / WT2)) % (H / HT);    // 0..11
    const int n  = bid / ((W / WT2) * (H / HT));    // 0..15
    const int r0p = hb * HT;                        // padded-row base of tile
    const int c0p = wb * WT2;                       // padded-col base
    const unsigned short* xbn = xb + (size_t)n * 4 * HP * WP * 8;

    // ---- staging: 3840 granules over 512 threads; 7 sweeps + 256 tail ----
    #pragma unroll
    for (int it = 0; it < 7; ++it) {
        const int idx = it * 512 + t;
        const int w = idx % RC2;
        const int r = (idx / RC2) % RROWS;
        const int quad = idx / (RC2 * RROWS);
        const size_t goff = (((size_t)(quad * HP + r0p + r)) * WP + (c0p + w)) * 8;
        gload_lds16(xbn + goff, &ldsx[(size_t)idx * 8]);
    }
    if (t < 256) {   // waves 0-3 active, 4-7 skip: wave-uniform
        const int idx = 3584 + t;
        const int w = idx % RC2;
        const int r = (idx / RC2) % RROWS;
        const int quad = idx / (RC2 * RROWS);
        const size_t goff = (((size_t)(quad * HP + r0p + r)) * WP + (c0p + w)) * 8;
        gload_lds16(xbn + goff, &ldsx[(size_t)idx * 8]);
    }

    const int wave = t >> 6;            // 0..7 -> out rows wave*2, wave*2+1
    const int lane = t & 63;
    const int l31 = lane & 31;          // A: och / B: pixel col / D: col
    const int oct = lane >> 5;          // A/B: k-octet (8 ch) / D: och bits

    // acc init = bias (D = A*B + C): och = (reg&3) + 4*oct + 8*(reg>>2)
    f32x16 acc0, acc1;
    #pragma unroll
    for (int reg = 0; reg < 16; reg++) {
        const float bv = bias[(reg & 3) + 4 * oct + 8 * (reg >> 2)];
        acc0[reg] = bv;
        acc1[reg] = bv;
    }

    // per-lane A base: frag idx = (tap*2+half)*64 + oct*32 + l31
    const bf16x8* __restrict__ Ap = (const bf16x8*)W3 + (oct * 32 + l31);
    // per-lane B base (shorts): [(oct*RROWS + wave*2)*RC2 + l31] granules;
    // offset per (half,sidx,dx) = (half*2*RROWS*RC2 + sidx*RC2 + dx)*8 shorts
    const unsigned short* bbase = &ldsx[(size_t)((oct * RROWS + wave * 2) * RC2 + l31) * 8];

    // preload unit 0 (dx=0, half=0)
    bf16x8 A[2][9];
    #pragma unroll
    for (int dy = 0; dy < 9; dy++)
        A[0][dy] = Ap[(dy * 9) * 2 * 64];

    __syncthreads();   // drains vmcnt -> staged data visible in LDS

    #pragma unroll
    for (int dx = 0; dx < 9; dx++) {
        #pragma unroll
        for (int half = 0; half < 2; half++) {
            const int u = dx * 2 + half;
            const int h = u & 1;
            if (u < 17) {
                const int nu = u + 1;
                const int ndx = nu >> 1, nhalf = nu & 1;
                #pragma unroll
                for (int dy = 0; dy < 9; dy++)
                    A[h ^ 1][dy] = Ap[((dy * 9 + ndx) * 2 + nhalf) * 64];
            }
            __builtin_amdgcn_s_setprio(1);
            #pragma unroll
            for (int sidx = 0; sidx < 10; sidx++) {
                const bf16x8 bfrag = *(const bf16x8*)
                    &bbase[(size_t)(half * (2 * RROWS * RC2) + sidx * RC2 + dx) * 8];
                if (sidx < 9)
                    acc0 = __builtin_amdgcn_mfma_f32_32x32x16_bf16(
                        A[h][sidx], bfrag, acc0, 0, 0, 0);
                if (sidx > 0)
                    acc1 = __builtin_amdgcn_mfma_f32_32x32x16_bf16(
                        A[h][sidx - 1], bfrag, acc1, 0, 0, 0);
            }
            __builtin_amdgcn_s_setprio(0);
        }
    }

    // ---- epilogue: D col = lane&31 (pixel), och = (reg&3)+4*oct+8*(reg>>2) ----
    float* outn = out + (size_t)n * NOUT * H * W;
    const int col = c0p + l31;
    const int row0 = r0p + wave * 2;
    #pragma unroll
    for (int reg = 0; reg < 16; reg++) {
        const int och = (reg & 3) + 4 * oct + 8 * (reg >> 2);
        float* p = &outn[((size_t)och * H + row0) * W + col];
        p[0] = acc0[reg];
        p[W] = acc1[reg];
    }
}

// ---- Legacy standalone genw (old layout, for fallback conv) ----
__global__ void genw_kernel(const float* __restrict__ wp, unsigned short* __restrict__ W2g) {
    const int b = blockIdx.x;
    const int o = b >> 5;
    const int i = b & 31;
    const int t = threadIdx.x;

    float sx = wp[b * 3 + 0], sy = wp[b * 3 + 1], th = wp[b * 3 + 2];
    float rad = th / 180.0f * 3.14159265358979323846f;
    float co = cosf(rad), si = sinf(rad);
    float sx2 = sx * sx, sy2 = sy * sy;
    float a = co * co * sx2 + si * si * sy2;
    float bb = co * si * (sx2 - sy2);
    float d = si * si * sx2 + co * co * sy2;
    float det = a * d - bb * bb;
    float ia = d / det, ib = -bb / det, idd = a / det;

    const int tap = t;
    float e = 0.0f;
    if (tap < 81) {
        float xx = (float)(tap % 9 - 4);
        float yy = (float)(tap / 9 - 4);
        float q = ia * xx * xx + 2.0f * ib * xx * yy + idd * yy * yy;
        e = expf(-0.5f * q);
    }
    float s = e;
    #pragma unroll
    for (int off = 32; off > 0; off >>= 1) s += __shfl_down(s, off);
    __shared__ float ws[2];
    if ((t & 63) == 0) ws[t >> 6] = s;
    __syncthreads();
    float total = ws[0] + ws[1];

    if (tap < 81) {
        int mt = o >> 4, m = o & 15, quad = i >> 3, j = i & 7;
        W2g[((((mt * 81 + tap) * 4 + quad) * 16 + m) << 3) + j] = f2bf(e / total);
    }
}

// ---- Legacy conv kernel (fallback if workspace too small) ----
__global__ __launch_bounds__(256, 4) void conv_kernel_legacy(
    const float* __restrict__ x, const unsigned short* __restrict__ W2g,
    const float* __restrict__ bias, float* __restrict__ out)
{
    __shared__ __align__(16) unsigned short ldsx[4 * RROWS * RCOLS * 8];

    const int t = threadIdx.x;
    const int bid = (blockIdx.x & 7) * 288 + (blockIdx.x >> 3);
    const int wb = bid % (W / WTL);
    const int hb = (bid / (W / WTL)) % (H / HT);
    const int n  = bid / ((W / WTL) * (H / HT));
    const int row0 = hb * HT - PADI;
    const int col0 = wb * WTL - PADI;
    const float* xn = x + (size_t)n * CIN * H * W;

    float v[9][8];
    #pragma unroll
    for (int it = 0; it < 9; ++it) {
        int idx = it * 256 + t;
        int w = idx % RCOLS;
        int r = (idx / RCOLS) % RROWS;
        int quad = idx / (RCOLS * RROWS);
        int row = row0 + r, col = col0 + w;
        #pragma unroll
        for (int k = 0; k < 8; k++) v[it][k] = 0.0f;
        if ((unsigned)row < (unsigned)H && (unsigned)col < (unsigned)W) {
            const float* p = xn + ((size_t)(quad * 8) * H + row) * W + col;
            #pragma unroll
            for (int k = 0; k < 8; k++) v[it][k] = p[(size_t)k * H * W];
        }
    }
    #pragma unroll
    for (int it = 0; it < 9; ++it) {
        int idx = it * 256 + t;
        unsigned int d[4];
        #pragma unroll
        for (int k = 0; k < 4; k++)
            d[k] = (unsigned int)f2bf(v[it][2 * k]) | ((unsigned int)f2bf(v[it][2 * k + 1]) << 16);
        *(uint4*)&ldsx[(size_t)idx * 8] = make_uint4(d[0], d[1], d[2], d[3]);
    }

    const int wave = t >> 6;
    const int lane = t & 63;
    const int l15 = lane & 15;
    const int quad4 = lane >> 4;
    const int mt = wave & 1;
    const int rbase = (wave >> 1) * 8;

    const bf16x8* __restrict__ Wpt = (const bf16x8*)W2g;

    bf16x8 A[2][9];
    #pragma unroll
    for (int dy = 0; dy < 9; dy++)
        A[0][dy] = Wpt[((mt * 81 + dy * 9 + 0) * 4 + quad4) * 16 + l15];

    __syncthreads();

    f32x4 acc[8];
    #pragma unroll
    for (int i = 0; i < 8; i++) acc[i] = (f32x4){0.f, 0.f, 0.f, 0.f};

    const unsigned short* bptr = &ldsx[(size_t)(((quad4 * RROWS + rbase) * RCOLS) + l15) * 8];

    #pragma unroll
    for (int dx = 0; dx < 9; dx++) {
        const int cur = dx & 1, nxt = cur ^ 1;
        if (dx < 8) {
            #pragma unroll
            for (int dy = 0; dy < 9; dy++)
                A[nxt][dy] = Wpt[((mt * 81 + dy * 9 + (dx + 1)) * 4 + quad4) * 16 + l15];
        }
        #pragma unroll
        for (int rr = 0; rr < 16; rr++) {
            const bf16x8 bfrag = *(const bf16x8*)&bptr[(size_t)(rr * RCOLS + dx) * 8];
            #pragma unroll
            for (int dy = 0; dy < 9; dy++) {
                const int orr = rr - dy;
                if (orr >= 0 && orr < 8) {
                    acc[orr] = __builtin_amdgcn_mfma_f32_16x16x32_bf16(
                        A[cur][dy], bfrag, acc[orr], 0, 0, 0);
                }
            }
        }
    }

    float* outn = out + (size_t)n * NOUT * H * W;
    float bb[4];
    #pragma unroll
    for (int reg = 0; reg < 4; reg++) bb[reg] = bias[mt * 16 + quad4 * 4 + reg];
    #pragma unroll
    for (int orr = 0; orr < 8; orr++) {
        const int row = hb * HT + rbase + orr;
        const int col = wb * WTL + l15;
        #pragma unroll
        for (int reg = 0; reg < 4; reg++) {
            const int och = mt * 16 + quad4 * 4 + reg;
            outn[((size_t)och * H + row) * W + col] = acc[orr][reg] + bb[reg];
        }
    }
}

extern "C" void kernel_launch(void* const* d_in, const int* in_sizes, int n_in,
                              void* d_out, int out_size, void* d_ws, size_t ws_size,
                              hipStream_t stream) {
    const float* x    = (const float*)d_in[0];
    const float* wp   = (const float*)d_in[1];   // (32,32,3)
    const float* bias = (const float*)d_in[2];   // (32,)
    float* out = (float*)d_out;

    unsigned short* Wg = (unsigned short*)d_ws;                // 165,888 B
    const size_t XB_OFF  = 262144;                             // 256 KiB
    const size_t XB_BYTES = (size_t)NB * 4 * HP * WP * 8 * 2;  // 40,960,000 B
    unsigned short* xb = (unsigned short*)((char*)d_ws + XB_OFF);

    if (ws_size >= XB_OFF + XB_BYTES) {
        genw32_kernel<<<NOUT * CIN, 128, 0, stream>>>(wp, Wg);
        const int xpad_blocks = (NB * 4 * HP * WP) / 256;      // 10,000
        xpad_kernel<<<xpad_blocks, 256, 0, stream>>>(x, xb);
        conv_kernel<<<NT2, 512, 0, stream>>>(xb, Wg, bias, out);
    } else {
        genw_kernel<<<NOUT * CIN, 128, 0, stream>>>(wp, Wg);
        const int blocks = NB * (H / HT) * (W / WTL);          // 2304
        conv_kernel_legacy<<<blocks, 256, 0, stream>>>(x, Wg, bias, out);
    }
}

// Round 6
// 188.423 us; speedup vs baseline: 1.5164x; 1.5164x over previous
//
#include <hip/hip_runtime.h>
#include <stdint.h>

#define H 192
#define W 192
#define CIN 32
#define NOUT 32
#define NB 16
#define PADI 4

#define HT 16          // output rows per block
#define WTL 16         // output cols per block
#define RROWS 24       // HT + 8 halo
#define RCOLS 24       // WTL + 8 halo

typedef __attribute__((ext_vector_type(8))) short bf16x8;
typedef __attribute__((ext_vector_type(4))) float f32x4;

__device__ __forceinline__ unsigned short f2bf(float f) {
    union { float f; unsigned int u; } v; v.f = f;
    unsigned int r = v.u + 0x7fffu + ((v.u >> 16) & 1u);
    return (unsigned short)(r >> 16);
}

// HW round-to-nearest-even pack of 2 f32 -> 2 bf16 in one VALU op.
// (Same rounding as f2bf; no builtin exists on gfx950, so inline asm.)
__device__ __forceinline__ unsigned int cvtpk_bf16(float lo, float hi) {
    unsigned int r;
    asm("v_cvt_pk_bf16_f32 %0, %1, %2" : "=v"(r) : "v"(lo), "v"(hi));
    return r;
}

// ---- Gaussian kernel generation: one block per (o,i) pair, one thread per tap ----
// Output layout (bf16 as ushort): W2g[mt][tap][quad][m][j]  (mt=o>>4, m=o&15, quad=i>>3, j=i&7)
__global__ void genw_kernel(const float* __restrict__ wp, unsigned short* __restrict__ W2g) {
    const int b = blockIdx.x;          // = o*32 + i
    const int o = b >> 5;
    const int i = b & 31;
    const int t = threadIdx.x;         // 0..127

    float sx = wp[b * 3 + 0], sy = wp[b * 3 + 1], th = wp[b * 3 + 2];
    float rad = th / 180.0f * 3.14159265358979323846f;
    float co = cosf(rad), si = sinf(rad);
    float sx2 = sx * sx, sy2 = sy * sy;
    float a = co * co * sx2 + si * si * sy2;
    float bb = co * si * (sx2 - sy2);
    float d = si * si * sx2 + co * co * sy2;
    float det = a * d - bb * bb;
    float ia = d / det, ib = -bb / det, idd = a / det;

    const int tap = t;
    float e = 0.0f;
    if (tap < 81) {
        float xx = (float)(tap % 9 - 4);
        float yy = (float)(tap / 9 - 4);
        float q = ia * xx * xx + 2.0f * ib * xx * yy + idd * yy * yy;
        e = expf(-0.5f * q);
    }
    // reduce across 128 threads (2 waves)
    float s = e;
    #pragma unroll
    for (int off = 32; off > 0; off >>= 1) s += __shfl_down(s, off);
    __shared__ float ws[2];
    if ((t & 63) == 0) ws[t >> 6] = s;
    __syncthreads();
    float total = ws[0] + ws[1];

    if (tap < 81) {
        int mt = o >> 4, m = o & 15, quad = i >> 3, j = i & 7;
        W2g[((((mt * 81 + tap) * 4 + quad) * 16 + m) << 3) + j] = f2bf(e / total);
    }
}

// ---- Conv kernel: implicit GEMM (R0-champion structure) ----
// Block: 256 thr = 4 waves; tile 16 rows x 16 cols, 32 och.
// Wave w: mt = w&1 (16 och), rows [(w>>1)*8, +8) of the tile.
// LDS x-tile layout: [quad][r][w][8ch] (16B granules, lane-linear => conflict-free).
// Changes vs R0: (1) bf16 pack uses v_cvt_pk_bf16_f32 (1 op per 2 elems instead
// of ~10); (2) bias folded into acc init (D=A*B+C), epilogue adds deleted.
// Everything else identical to the 96.5us-proven kernel.
__global__ __launch_bounds__(256, 4) void conv_kernel(
    const float* __restrict__ x, const unsigned short* __restrict__ W2g,
    const float* __restrict__ bias, float* __restrict__ out)
{
    __shared__ __align__(16) unsigned short ldsx[4 * RROWS * RCOLS * 8];  // 36,864 B

    const int t = threadIdx.x;
    // XCD-contiguous swizzle: 8 classes x 288 tiles (= 2 whole images per class)
    const int bid = (blockIdx.x & 7) * 288 + (blockIdx.x >> 3);
    const int wb = bid % (W / WTL);                 // 0..11
    const int hb = (bid / (W / WTL)) % (H / HT);    // 0..11
    const int n  = bid / ((W / WTL) * (H / HT));    // 0..15
    const int row0 = hb * HT - PADI;
    const int col0 = wb * WTL - PADI;
    const float* xn = x + (size_t)n * CIN * H * W;

    const int wave = t >> 6;
    const int lane = t & 63;
    const int l15 = lane & 15;      // A: m-row / B: pixel col / D: col
    const int quad4 = lane >> 4;    // A/B: k-group (8 ch) / D: och-quad
    const int mt = wave & 1;        // och tile (16 och)
    const int rbase = (wave >> 1) * 8;  // output-row base within tile

    // bias fragment (loaded early; folded into acc init below)
    float bb[4];
    #pragma unroll
    for (int reg = 0; reg < 4; reg++) bb[reg] = bias[mt * 16 + quad4 * 4 + reg];

    // ---- phase 1: issue ALL staging loads (72 fp32 in VGPRs) ----
    float v[9][8];
    #pragma unroll
    for (int it = 0; it < 9; ++it) {
        int idx = it * 256 + t;
        int w = idx % RCOLS;
        int r = (idx / RCOLS) % RROWS;
        int quad = idx / (RCOLS * RROWS);
        int row = row0 + r, col = col0 + w;
        #pragma unroll
        for (int k = 0; k < 8; k++) v[it][k] = 0.0f;
        if ((unsigned)row < (unsigned)H && (unsigned)col < (unsigned)W) {
            const float* p = xn + ((size_t)(quad * 8) * H + row) * W + col;
            #pragma unroll
            for (int k = 0; k < 8; k++) v[it][k] = p[(size_t)k * H * W];
        }
    }
    // ---- phase 2: pack (v_cvt_pk_bf16_f32) + LDS write (lane-linear b128) ----
    #pragma unroll
    for (int it = 0; it < 9; ++it) {
        int idx = it * 256 + t;
        unsigned int d[4];
        #pragma unroll
        for (int k = 0; k < 4; k++)
            d[k] = cvtpk_bf16(v[it][2 * k], v[it][2 * k + 1]);
        *(uint4*)&ldsx[(size_t)idx * 8] = make_uint4(d[0], d[1], d[2], d[3]);
    }

    const bf16x8* __restrict__ Wpt = (const bf16x8*)W2g;

    // preload A-frags for dx=0 (latency hidden under the barrier)
    bf16x8 A[2][9];
    #pragma unroll
    for (int dy = 0; dy < 9; dy++)
        A[0][dy] = Wpt[((mt * 81 + dy * 9 + 0) * 4 + quad4) * 16 + l15];

    __syncthreads();

    // acc init = bias (D = A*B + C); och = mt*16 + quad4*4 + reg
    f32x4 acc[8];
    #pragma unroll
    for (int i = 0; i < 8; i++)
        acc[i] = (f32x4){bb[0], bb[1], bb[2], bb[3]};

    const unsigned short* bptr = &ldsx[(size_t)(((quad4 * RROWS + rbase) * RCOLS) + l15) * 8];

    #pragma unroll
    for (int dx = 0; dx < 9; dx++) {
        const int cur = dx & 1, nxt = cur ^ 1;
        if (dx < 8) {
            #pragma unroll
            for (int dy = 0; dy < 9; dy++)
                A[nxt][dy] = Wpt[((mt * 81 + dy * 9 + (dx + 1)) * 4 + quad4) * 16 + l15];
        }
        #pragma unroll
        for (int rr = 0; rr < 16; rr++) {           // lds row rel to rbase; out_r = rr - dy
            const bf16x8 bfrag = *(const bf16x8*)&bptr[(size_t)(rr * RCOLS + dx) * 8];
            #pragma unroll
            for (int dy = 0; dy < 9; dy++) {
                const int orr = rr - dy;
                if (orr >= 0 && orr < 8) {
                    acc[orr] = __builtin_amdgcn_mfma_f32_16x16x32_bf16(
                        A[cur][dy], bfrag, acc[orr], 0, 0, 0);
                }
            }
        }
    }

    // ---- epilogue: D layout col = lane&15 (pixel), row = quad4*4 + reg (och) ----
    // bias already in acc.
    float* outn = out + (size_t)n * NOUT * H * W;
    #pragma unroll
    for (int orr = 0; orr < 8; orr++) {
        const int row = hb * HT + rbase + orr;
        const int col = wb * WTL + l15;
        #pragma unroll
        for (int reg = 0; reg < 4; reg++) {
            const int och = mt * 16 + quad4 * 4 + reg;
            outn[((size_t)och * H + row) * W + col] = acc[orr][reg];
        }
    }
}

extern "C" void kernel_launch(void* const* d_in, const int* in_sizes, int n_in,
                              void* d_out, int out_size, void* d_ws, size_t ws_size,
                              hipStream_t stream) {
    const float* x    = (const float*)d_in[0];
    const float* wp   = (const float*)d_in[1];   // (32,32,3)
    const float* bias = (const float*)d_in[2];   // (32,)
    float* out = (float*)d_out;
    unsigned short* W2g = (unsigned short*)d_ws; // 165,888 B of scratch

    genw_kernel<<<NOUT * CIN, 128, 0, stream>>>(wp, W2g);
    const int blocks = NB * (H / HT) * (W / WTL);   // 16*12*12 = 2304
    conv_kernel<<<blocks, 256, 0, stream>>>(x, W2g, bias, out);
}